// Round 1
// baseline (243.399 us; speedup 1.0000x reference)
//
#include <hip/hip_runtime.h>
#include <cmath>

// SelfMutualAttention: b=2, c=256, h=w=64 (n=4096), H=8 heads, d=32.
// Plan: bf16-MFMA everywhere, flash-style fused attention (no SxS matrix).
//  k1 qkv_proj: Q/K -> [b][n][256] bf16 (Q pre-scaled by d^-0.5 * log2e), V -> [b][256][n] bf16
//  k2 attn:     per-wave 32 q-rows, swapped QK^T (S^T=K.Q^T) so softmax is lane-local;
//               unnormalized exp2 accumulation, one divide at end; P via cvt_pk+permlane32_swap
//  k3 oproj:    O fp32 [b][n][256] -> Wo (hi/lo split both operands) -> fp32 [b][256][n]

typedef unsigned int u32;
typedef unsigned short u16;
typedef __attribute__((ext_vector_type(4))) float f32x4;
typedef __attribute__((ext_vector_type(16))) float f32x16;
typedef __attribute__((ext_vector_type(8))) short short8;
typedef __attribute__((ext_vector_type(2))) u32 u32x2;
typedef __attribute__((ext_vector_type(4))) u32 u32x4;

__device__ __forceinline__ u32 cvtpk_bf16(float a, float b) {
  u32 r; asm("v_cvt_pk_bf16_f32 %0, %1, %2" : "=v"(r) : "v"(a), "v"(b)); return r;
}
__device__ __forceinline__ void pl32swap(u32 &a, u32 &b) {
  asm("v_permlane32_swap_b32 %0, %1" : "+v"(a), "+v"(b));
}
__device__ __forceinline__ u16 f2bf(float x) { return (u16)cvtpk_bf16(x, x); }

__device__ __forceinline__ f32x16 mfma16(short8 a, short8 b, f32x16 c) {
  return __builtin_amdgcn_mfma_f32_32x32x16_bf16(a, b, c, 0, 0, 0);
}

// split a float into hi-bf16 (truncated) + lo-bf16 (residual, RNE) pairs packed as words
__device__ __forceinline__ void split2(float a, float b, u32 &hw, u32 &lw) {
  u32 ua = __builtin_bit_cast(u32, a), ub = __builtin_bit_cast(u32, b);
  hw = (ua >> 16) | (ub & 0xffff0000u);
  float ra = a - __builtin_bit_cast(float, ua & 0xffff0000u);
  float rb = b - __builtin_bit_cast(float, ub & 0xffff0000u);
  lw = cvtpk_bf16(ra, rb);
}
__device__ __forceinline__ void split8(f32x4 a, f32x4 b, short8 &hf, short8 &lf) {
  u32 h0,l0,h1,l1,h2,l2,h3,l3;
  split2(a[0],a[1],h0,l0); split2(a[2],a[3],h1,l1);
  split2(b[0],b[1],h2,l2); split2(b[2],b[3],h3,l3);
  u32x4 hv = {h0,h1,h2,h3}, lv = {l0,l1,l2,l3};
  hf = __builtin_bit_cast(short8, hv);
  lf = __builtin_bit_cast(short8, lv);
}
__device__ __forceinline__ short8 pack8(f32x4 a, f32x4 b) {
  u32x4 v = { cvtpk_bf16(a[0],a[1]), cvtpk_bf16(a[2],a[3]),
              cvtpk_bf16(b[0],b[1]), cvtpk_bf16(b[2],b[3]) };
  return __builtin_bit_cast(short8, v);
}

#define LDK 40  // halfword stride of transposed X tile row (16B-aligned reads, de-conflicted)

// ---------------- k1: fused Q/K/V projection -------------------------------
// grid (32 nblk, 4 cblk, 6 = batch*3+mode is z%3=mode, z/3=batch), 256 thr
__global__ __launch_bounds__(256) void qkv_proj_kernel(
    const float* __restrict__ X,
    const float* __restrict__ Wq, const float* __restrict__ bq,
    const float* __restrict__ Wk, const float* __restrict__ bk,
    const float* __restrict__ Wv, const float* __restrict__ bv,
    u16* __restrict__ Qs, u16* __restrict__ Ks, u16* __restrict__ Vt)
{
  const int mode = blockIdx.z % 3;
  const int b    = blockIdx.z / 3;
  const float* W    = mode==0 ? Wq : (mode==1 ? Wk : Wv);
  const float* bias = mode==0 ? bq : (mode==1 ? bk : bv);
  u16* Out          = mode==0 ? Qs : (mode==1 ? Ks : Vt);
  const float qmul  = mode==0 ? (0.17677669529663689f * 1.4426950408889634f) : 1.0f;

  const int c0 = blockIdx.y * 64;
  const int n0 = blockIdx.x * 128;
  const int tid = threadIdx.x;
  const int l = tid & 63, wv = tid >> 6;
  const int lane31 = l & 31, hi = l >> 5;
  const int wc = wv >> 1, wn = wv & 1;
  const int crow = c0 + wc*32 + lane31;

  __shared__ u16 xt[128 * LDK];

  f32x16 acc0 = {}, acc1 = {};

  for (int kk = 0; kk < 256; kk += 32) {
    __syncthreads();
    // stage X[kk..kk+31][n0..n0+127] transposed to xt[n][k], bf16
    #pragma unroll
    for (int t = 0; t < 2; t++) {
      int task = tid + t*256;          // 512 tasks = 16 k-pairs x 32 n-chunks
      int pair = task >> 5;            // 0..15 (covers k rows 2*pair, 2*pair+1)
      int nc0  = (task & 31) * 4;
      const float* px = X + ((size_t)b*256 + kk + pair*2) * 4096 + n0 + nc0;
      f32x4 xa = *(const f32x4*)px;
      f32x4 xb = *(const f32x4*)(px + 4096);
      #pragma unroll
      for (int i = 0; i < 4; i++) {
        u32 packed = cvtpk_bf16(xa[i], xb[i]);   // lo=k even, hi=k odd
        *(u32*)(&xt[(nc0+i)*LDK + pair*2]) = packed;
      }
    }
    __syncthreads();
    #pragma unroll
    for (int ks = 0; ks < 2; ks++) {
      const float* pw = W + (size_t)crow*256 + kk + ks*16 + hi*8;
      short8 wh, wl;
      split8(*(const f32x4*)pw, *(const f32x4*)(pw+4), wh, wl);
      short8 bf0 = *(const short8*)(&xt[(wn*64 +      lane31)*LDK + ks*16 + hi*8]);
      short8 bf1 = *(const short8*)(&xt[(wn*64 + 32 + lane31)*LDK + ks*16 + hi*8]);
      acc0 = mfma16(wh, bf0, acc0);
      acc0 = mfma16(wl, bf0, acc0);
      acc1 = mfma16(wh, bf1, acc1);
      acc1 = mfma16(wl, bf1, acc1);
    }
  }

  if (mode == 2) {
    // V: [b][c][n] (natural) -- coalesced 64B runs
    #pragma unroll
    for (int r = 0; r < 16; r++) {
      int row = (r&3) + 8*(r>>2) + 4*hi;
      int c = c0 + wc*32 + row;
      float bv2 = bias[c];
      size_t o = ((size_t)b*256 + c) * 4096 + n0 + wn*64 + lane31;
      Out[o]      = f2bf(acc0[r] + bv2);
      Out[o + 32] = f2bf(acc1[r] + bv2);
    }
  } else {
    // Q/K: [b][n][c] -- per-lane packed dwordx2 stores
    int n = n0 + wn*64 + lane31;
    #pragma unroll
    for (int j = 0; j < 2; j++) {
      const f32x16 &a = j ? acc1 : acc0;
      size_t nbase = ((size_t)b*4096 + n + j*32) << 8;
      #pragma unroll
      for (int g = 0; g < 4; g++) {
        int cb = c0 + wc*32 + 8*g + 4*hi;
        float v0 = (a[4*g+0] + bias[cb+0]) * qmul;
        float v1 = (a[4*g+1] + bias[cb+1]) * qmul;
        float v2 = (a[4*g+2] + bias[cb+2]) * qmul;
        float v3 = (a[4*g+3] + bias[cb+3]) * qmul;
        u32x2 pk = { cvtpk_bf16(v0, v1), cvtpk_bf16(v2, v3) };
        *(u32x2*)(&Out[nbase + cb]) = pk;
      }
    }
  }
}

// ---------------- k2: fused flash attention --------------------------------
// grid 512 blocks x 256 thr; block = 4 independent waves, each owns 32 q-rows.
__global__ __launch_bounds__(256) void attn_kernel(
    const u16* __restrict__ Qs, const u16* __restrict__ Ks,
    const u16* __restrict__ Vt, float* __restrict__ Os)
{
  // XCD swizzle: all 32 q-blocks of one (b,h) on one XCD -> KV L2-resident
  const int fid  = blockIdx.x;
  const int xcd  = fid & 7, j8 = fid >> 3;
  const int bh   = xcd + 8*(j8 >> 5);
  const int qblk = j8 & 31;
  const int b = bh >> 3, h = bh & 7;

  const int tid = threadIdx.x, wv = tid >> 6, l = tid & 63;
  const int lane31 = l & 31, hi = l >> 5;
  const int q = qblk*128 + wv*32 + lane31;

  const size_t qoff = (((size_t)b*4096 + q) << 8) + h*32 + hi*8;
  short8 qf0 = *(const short8*)(Qs + qoff);        // d 0..15 slice (per-lane half)
  short8 qf1 = *(const short8*)(Qs + qoff + 16);   // d 16..31

  f32x16 acc = {};
  float lsum = 0.f;

  const u16* kbase = Ks + (((size_t)b*4096 + lane31) << 8) + h*32 + hi*8;
  const u16* vbase = Vt + (((size_t)(b*8 + h)*32 + lane31) << 12) + hi*8;

  for (int kv0 = 0; kv0 < 4096; kv0 += 32) {
    const u16* kp = kbase + ((size_t)kv0 << 8);
    short8 kf0 = *(const short8*)(kp);
    short8 kf1 = *(const short8*)(kp + 16);
    f32x16 s = {};
    s = mfma16(kf0, qf0, s);   // S^T[kv][q]: lane owns q=lane31, 16 kv rows in regs
    s = mfma16(kf1, qf1, s);

    float p[16];
    #pragma unroll
    for (int r = 0; r < 16; r++) p[r] = exp2f(s[r]);   // log2e folded into Q
    #pragma unroll
    for (int r = 0; r < 16; r++) lsum += p[r];

    // P^T -> A-fragment for PV: pack pairs, swap halves across lane 32 boundary
    u32 a0 = cvtpk_bf16(p[0],p[1]),  b0 = cvtpk_bf16(p[4],p[5]);
    u32 c1 = cvtpk_bf16(p[2],p[3]),  d1 = cvtpk_bf16(p[6],p[7]);
    u32 e0 = cvtpk_bf16(p[8],p[9]),  f0 = cvtpk_bf16(p[12],p[13]);
    u32 g1 = cvtpk_bf16(p[10],p[11]), h1 = cvtpk_bf16(p[14],p[15]);
    pl32swap(a0, b0); pl32swap(c1, d1); pl32swap(e0, f0); pl32swap(g1, h1);
    u32x4 pa0u = {a0, c1, b0, d1}, pa1u = {e0, g1, f0, h1};
    short8 pa0 = __builtin_bit_cast(short8, pa0u);
    short8 pa1 = __builtin_bit_cast(short8, pa1u);

    const u16* vp = vbase + kv0;
    short8 vf0 = *(const short8*)(vp);
    short8 vf1 = *(const short8*)(vp + 16);
    acc = mfma16(pa0, vf0, acc);   // out[q][dv] += P[q][kv] V[kv][dv]
    acc = mfma16(pa1, vf1, acc);
  }

  float L = lsum + __shfl_xor(lsum, 32);
  float Linv = 1.0f / L;
  #pragma unroll
  for (int r = 0; r < 16; r++) {
    int row = (r&3) + 8*(r>>2) + 4*hi;
    float Lr = __shfl(Linv, row);        // lane `row` holds 1/L for q-row `row`
    int qg = qblk*128 + wv*32 + row;
    Os[(((size_t)b*4096 + qg) << 8) + h*32 + lane31] = acc[r] * Lr;
  }
}

// ---------------- k3: output projection ------------------------------------
__global__ __launch_bounds__(256) void oproj_kernel(
    const float* __restrict__ O, const float* __restrict__ Wo,
    const float* __restrict__ bo, float* __restrict__ Out)
{
  const int b = blockIdx.z, c0 = blockIdx.y*64, n0 = blockIdx.x*128;
  const int tid = threadIdx.x, wv = tid >> 6, l = tid & 63;
  const int lane31 = l & 31, hi = l >> 5;
  const int wc = wv >> 1, wn = wv & 1;
  const int crow = c0 + wc*32 + lane31;
  f32x16 acc0 = {}, acc1 = {};

  for (int kk = 0; kk < 256; kk += 16) {
    const float* pw = Wo + (size_t)crow*256 + kk + hi*8;
    short8 wh, wl;
    split8(*(const f32x4*)pw, *(const f32x4*)(pw+4), wh, wl);
    #pragma unroll
    for (int j = 0; j < 2; j++) {
      const float* po = O + (((size_t)b*4096 + n0 + wn*64 + j*32 + lane31) << 8) + kk + hi*8;
      short8 oh, ol;
      split8(*(const f32x4*)po, *(const f32x4*)(po+4), oh, ol);
      f32x16 &a = j ? acc1 : acc0;
      a = mfma16(wh, oh, a);
      a = mfma16(wh, ol, a);
      a = mfma16(wl, oh, a);
    }
  }
  #pragma unroll
  for (int r = 0; r < 16; r++) {
    int row = (r&3) + 8*(r>>2) + 4*hi;
    int c = c0 + wc*32 + row;
    float bv = bo[c];
    size_t o = ((size_t)b*256 + c)*4096 + n0 + wn*64 + lane31;
    Out[o]      = acc0[r] + bv;
    Out[o + 32] = acc1[r] + bv;
  }
}

extern "C" void kernel_launch(void* const* d_in, const int* in_sizes, int n_in,
                              void* d_out, int out_size, void* d_ws, size_t ws_size,
                              hipStream_t stream) {
  const float* x1 = (const float*)d_in[0];
  const float* Wq = (const float*)d_in[1];
  const float* bq = (const float*)d_in[2];
  const float* Wk = (const float*)d_in[3];
  const float* bk = (const float*)d_in[4];
  const float* Wv = (const float*)d_in[5];
  const float* bv = (const float*)d_in[6];
  const float* Wo = (const float*)d_in[7];
  const float* bo = (const float*)d_in[8];

  const size_t NEL = (size_t)2 * 4096 * 256;   // 2M elements per tensor
  u16* Qs = (u16*)d_ws;
  u16* Ks = Qs + NEL;
  u16* Vt = Ks + NEL;
  float* Os = (float*)(Vt + NEL);              // fp32 O, [b][n][256]
  float* out = (float*)d_out;

  qkv_proj_kernel<<<dim3(32, 4, 6), 256, 0, stream>>>(x1, Wq, bq, Wk, bk, Wv, bv, Qs, Ks, Vt);
  attn_kernel<<<dim3(512), 256, 0, stream>>>(Qs, Ks, Vt, Os);
  oproj_kernel<<<dim3(32, 4, 2), 256, 0, stream>>>(Os, Wo, bo, out);
}

// Round 2
// 230.724 us; speedup vs baseline: 1.0549x; 1.0549x over previous
//
#include <hip/hip_runtime.h>
#include <cmath>

// SelfMutualAttention: b=2, c=256, h=w=64 (n=4096), H=8 heads, d=32.
//  k1 qkv_proj: Q/K -> [b][n][256] bf16 (Q pre-scaled by d^-0.5 * log2e), V -> [b][256][n] bf16
//  k2 attn:     flash, swapped QK^T, unnormalized exp2 accumulation.
//               R1: split-KV x4 within block (4 waves share one q-tile, LDS combine),
//               depth-1 register prefetch of K/V tiles, grid 2048 blocks.
//  k3 oproj:    O fp32 [b][n][256] -> Wo (hi/lo split both operands) -> fp32 [b][256][n]

typedef unsigned int u32;
typedef unsigned short u16;
typedef __attribute__((ext_vector_type(4))) float f32x4;
typedef __attribute__((ext_vector_type(16))) float f32x16;
typedef __attribute__((ext_vector_type(8))) short short8;
typedef __attribute__((ext_vector_type(2))) u32 u32x2;
typedef __attribute__((ext_vector_type(4))) u32 u32x4;

__device__ __forceinline__ u32 cvtpk_bf16(float a, float b) {
  u32 r; asm("v_cvt_pk_bf16_f32 %0, %1, %2" : "=v"(r) : "v"(a), "v"(b)); return r;
}
__device__ __forceinline__ void pl32swap(u32 &a, u32 &b) {
  asm("v_permlane32_swap_b32 %0, %1" : "+v"(a), "+v"(b));
}
__device__ __forceinline__ u16 f2bf(float x) { return (u16)cvtpk_bf16(x, x); }

__device__ __forceinline__ f32x16 mfma16(short8 a, short8 b, f32x16 c) {
  return __builtin_amdgcn_mfma_f32_32x32x16_bf16(a, b, c, 0, 0, 0);
}

// split a float into hi-bf16 (truncated) + lo-bf16 (residual, RNE) pairs packed as words
__device__ __forceinline__ void split2(float a, float b, u32 &hw, u32 &lw) {
  u32 ua = __builtin_bit_cast(u32, a), ub = __builtin_bit_cast(u32, b);
  hw = (ua >> 16) | (ub & 0xffff0000u);
  float ra = a - __builtin_bit_cast(float, ua & 0xffff0000u);
  float rb = b - __builtin_bit_cast(float, ub & 0xffff0000u);
  lw = cvtpk_bf16(ra, rb);
}
__device__ __forceinline__ void split8(f32x4 a, f32x4 b, short8 &hf, short8 &lf) {
  u32 h0,l0,h1,l1,h2,l2,h3,l3;
  split2(a[0],a[1],h0,l0); split2(a[2],a[3],h1,l1);
  split2(b[0],b[1],h2,l2); split2(b[2],b[3],h3,l3);
  u32x4 hv = {h0,h1,h2,h3}, lv = {l0,l1,l2,l3};
  hf = __builtin_bit_cast(short8, hv);
  lf = __builtin_bit_cast(short8, lv);
}

#define LDK 40  // halfword stride of transposed X tile row (16B-aligned reads, de-conflicted)

// ---------------- k1: fused Q/K/V projection -------------------------------
// grid (32 nblk, 4 cblk, 6 = batch*3+mode), 256 thr
__global__ __launch_bounds__(256) void qkv_proj_kernel(
    const float* __restrict__ X,
    const float* __restrict__ Wq, const float* __restrict__ bq,
    const float* __restrict__ Wk, const float* __restrict__ bk,
    const float* __restrict__ Wv, const float* __restrict__ bv,
    u16* __restrict__ Qs, u16* __restrict__ Ks, u16* __restrict__ Vt)
{
  const int mode = blockIdx.z % 3;
  const int b    = blockIdx.z / 3;
  const float* W    = mode==0 ? Wq : (mode==1 ? Wk : Wv);
  const float* bias = mode==0 ? bq : (mode==1 ? bk : bv);
  u16* Out          = mode==0 ? Qs : (mode==1 ? Ks : Vt);
  const float qmul  = mode==0 ? (0.17677669529663689f * 1.4426950408889634f) : 1.0f;

  const int c0 = blockIdx.y * 64;
  const int n0 = blockIdx.x * 128;
  const int tid = threadIdx.x;
  const int l = tid & 63, wv = tid >> 6;
  const int lane31 = l & 31, hi = l >> 5;
  const int wc = wv >> 1, wn = wv & 1;
  const int crow = c0 + wc*32 + lane31;

  __shared__ u16 xt[128 * LDK];

  f32x16 acc0 = {}, acc1 = {};

  for (int kk = 0; kk < 256; kk += 32) {
    __syncthreads();
    #pragma unroll
    for (int t = 0; t < 2; t++) {
      int task = tid + t*256;
      int pair = task >> 5;
      int nc0  = (task & 31) * 4;
      const float* px = X + ((size_t)b*256 + kk + pair*2) * 4096 + n0 + nc0;
      f32x4 xa = *(const f32x4*)px;
      f32x4 xb = *(const f32x4*)(px + 4096);
      #pragma unroll
      for (int i = 0; i < 4; i++) {
        u32 packed = cvtpk_bf16(xa[i], xb[i]);
        *(u32*)(&xt[(nc0+i)*LDK + pair*2]) = packed;
      }
    }
    __syncthreads();
    #pragma unroll
    for (int ks = 0; ks < 2; ks++) {
      const float* pw = W + (size_t)crow*256 + kk + ks*16 + hi*8;
      short8 wh, wl;
      split8(*(const f32x4*)pw, *(const f32x4*)(pw+4), wh, wl);
      short8 bf0 = *(const short8*)(&xt[(wn*64 +      lane31)*LDK + ks*16 + hi*8]);
      short8 bf1 = *(const short8*)(&xt[(wn*64 + 32 + lane31)*LDK + ks*16 + hi*8]);
      acc0 = mfma16(wh, bf0, acc0);
      acc0 = mfma16(wl, bf0, acc0);
      acc1 = mfma16(wh, bf1, acc1);
      acc1 = mfma16(wl, bf1, acc1);
    }
  }

  if (mode == 2) {
    #pragma unroll
    for (int r = 0; r < 16; r++) {
      int row = (r&3) + 8*(r>>2) + 4*hi;
      int c = c0 + wc*32 + row;
      float bv2 = bias[c];
      size_t o = ((size_t)b*256 + c) * 4096 + n0 + wn*64 + lane31;
      Out[o]      = f2bf(acc0[r] + bv2);
      Out[o + 32] = f2bf(acc1[r] + bv2);
    }
  } else {
    int n = n0 + wn*64 + lane31;
    #pragma unroll
    for (int j = 0; j < 2; j++) {
      const f32x16 &a = j ? acc1 : acc0;
      size_t nbase = ((size_t)b*4096 + n + j*32) << 8;
      #pragma unroll
      for (int g = 0; g < 4; g++) {
        int cb = c0 + wc*32 + 8*g + 4*hi;
        float v0 = (a[4*g+0] + bias[cb+0]) * qmul;
        float v1 = (a[4*g+1] + bias[cb+1]) * qmul;
        float v2 = (a[4*g+2] + bias[cb+2]) * qmul;
        float v3 = (a[4*g+3] + bias[cb+3]) * qmul;
        u32x2 pk = { cvtpk_bf16(v0, v1), cvtpk_bf16(v2, v3) };
        *(u32x2*)(&Out[nbase + cb]) = pk;
      }
    }
  }
}

// ---------------- k2: fused flash attention --------------------------------
// grid 2048 blocks x 256 thr. Block = one 32-row q-tile of one (b,h);
// 4 waves each own a 1024-row KV quarter; LDS combine at the end.
__global__ __launch_bounds__(256, 4) void attn_kernel(
    const u16* __restrict__ Qs, const u16* __restrict__ Ks,
    const u16* __restrict__ Vt, float* __restrict__ Os)
{
  // XCD swizzle: all q-blocks of one (b,h) on one XCD -> KV L2-resident
  const int fid  = blockIdx.x;
  const int xcd  = fid & 7, j = fid >> 3;       // j in [0,256)
  const int bh   = xcd + 8 * (j >> 7);          // 2 bh per XCD
  const int qblk = j & 127;
  const int b = bh >> 3, h = bh & 7;

  const int tid = threadIdx.x, wv = tid >> 6, l = tid & 63;
  const int lane31 = l & 31, hi = l >> 5;
  const int q = qblk*32 + lane31;

  const size_t qoff = (((size_t)b*4096 + q) << 8) + h*32 + hi*8;
  short8 qf0 = *(const short8*)(Qs + qoff);        // d 0..15 slice (per-lane half)
  short8 qf1 = *(const short8*)(Qs + qoff + 16);   // d 16..31

  f32x16 acc = {};
  float ls0 = 0.f, ls1 = 0.f, ls2 = 0.f, ls3 = 0.f;

  const u16* kbase = Ks + (((size_t)b*4096 + lane31) << 8) + h*32 + hi*8;
  const u16* vbase = Vt + (((size_t)(b*8 + h)*32 + lane31) << 12) + hi*8;

  int kv = wv * 1024;
  {
    const u16* kp = kbase + ((size_t)kv << 8);
    const u16* vp = vbase + kv;
  }
  short8 kc0 = *(const short8*)(kbase + ((size_t)kv << 8));
  short8 kc1 = *(const short8*)(kbase + ((size_t)kv << 8) + 16);
  short8 vc0 = *(const short8*)(vbase + kv);
  short8 vc1 = *(const short8*)(vbase + kv + 16);

  for (int it = 0; it < 32; ++it) {
    // depth-1 prefetch of next tile (wraps mod 4096 -> always valid memory)
    int kvn = (kv + 32) & 4095;
    const u16* kpn = kbase + ((size_t)kvn << 8);
    const u16* vpn = vbase + kvn;
    short8 kn0 = *(const short8*)(kpn);
    short8 kn1 = *(const short8*)(kpn + 16);
    short8 vn0 = *(const short8*)(vpn);
    short8 vn1 = *(const short8*)(vpn + 16);

    f32x16 s = {};
    s = mfma16(kc0, qf0, s);   // S^T[kv][q]: lane owns q=lane31, 16 kv rows in regs
    s = mfma16(kc1, qf1, s);

    float p[16];
    #pragma unroll
    for (int r = 0; r < 16; r++) p[r] = __builtin_amdgcn_exp2f(s[r]);  // log2e folded into Q
    ls0 += p[0] + p[1];  ls1 += p[2] + p[3];
    ls2 += p[4] + p[5];  ls3 += p[6] + p[7];
    ls0 += p[8] + p[9];  ls1 += p[10] + p[11];
    ls2 += p[12] + p[13]; ls3 += p[14] + p[15];

    // P^T -> A-fragment for PV: pack pairs, swap halves across lane 32 boundary
    u32 a0 = cvtpk_bf16(p[0],p[1]),  b0 = cvtpk_bf16(p[4],p[5]);
    u32 c1 = cvtpk_bf16(p[2],p[3]),  d1 = cvtpk_bf16(p[6],p[7]);
    u32 e0 = cvtpk_bf16(p[8],p[9]),  f0 = cvtpk_bf16(p[12],p[13]);
    u32 g1 = cvtpk_bf16(p[10],p[11]), h1 = cvtpk_bf16(p[14],p[15]);
    pl32swap(a0, b0); pl32swap(c1, d1); pl32swap(e0, f0); pl32swap(g1, h1);
    u32x4 pa0u = {a0, c1, b0, d1}, pa1u = {e0, g1, f0, h1};
    short8 pa0 = __builtin_bit_cast(short8, pa0u);
    short8 pa1 = __builtin_bit_cast(short8, pa1u);

    acc = mfma16(pa0, vc0, acc);   // out[q][dv] += P[q][kv] V[kv][dv]
    acc = mfma16(pa1, vc1, acc);

    kc0 = kn0; kc1 = kn1; vc0 = vn0; vc1 = vn1;
    kv = kvn;
  }

  // ---- combine the 4 KV-quarter partials via LDS ----
  __shared__ float accb[4][64][17];   // padded: stride 17 dwords -> conflict-free
  __shared__ float lsb[4][64];

  float lsum = (ls0 + ls1) + (ls2 + ls3);
  lsb[wv][l] = lsum;
  #pragma unroll
  for (int r = 0; r < 16; r++) accb[wv][l][r] = acc[r];
  __syncthreads();

  float Lt = (lsb[0][l] + lsb[1][l]) + (lsb[2][l] + lsb[3][l]);
  Lt += __shfl_xor(Lt, 32);
  float Linv = 1.0f / Lt;              // valid per q = lane31 (lanes hi=0 authoritative)

  // wave wv writes rows r in [wv*4, wv*4+4)
  #pragma unroll
  for (int i = 0; i < 4; i++) {
    int r = wv*4 + i;
    float o = (accb[0][l][r] + accb[1][l][r]) + (accb[2][l][r] + accb[3][l][r]);
    int row = (r&3) + 8*(r>>2) + 4*hi;
    float Lr = __shfl(Linv, row);      // lane `row` (hi=0) holds 1/L for q-row `row`
    int qg = qblk*32 + row;
    Os[(((size_t)b*4096 + qg) << 8) + h*32 + lane31] = o * Lr;
  }
}

// ---------------- k3: output projection ------------------------------------
__global__ __launch_bounds__(256) void oproj_kernel(
    const float* __restrict__ O, const float* __restrict__ Wo,
    const float* __restrict__ bo, float* __restrict__ Out)
{
  const int b = blockIdx.z, c0 = blockIdx.y*64, n0 = blockIdx.x*128;
  const int tid = threadIdx.x, wv = tid >> 6, l = tid & 63;
  const int lane31 = l & 31, hi = l >> 5;
  const int wc = wv >> 1, wn = wv & 1;
  const int crow = c0 + wc*32 + lane31;
  f32x16 acc0 = {}, acc1 = {};

  for (int kk = 0; kk < 256; kk += 16) {
    const float* pw = Wo + (size_t)crow*256 + kk + hi*8;
    short8 wh, wl;
    split8(*(const f32x4*)pw, *(const f32x4*)(pw+4), wh, wl);
    #pragma unroll
    for (int j = 0; j < 2; j++) {
      const float* po = O + (((size_t)b*4096 + n0 + wn*64 + j*32 + lane31) << 8) + kk + hi*8;
      short8 oh, ol;
      split8(*(const f32x4*)po, *(const f32x4*)(po+4), oh, ol);
      f32x16 &a = j ? acc1 : acc0;
      a = mfma16(wh, oh, a);
      a = mfma16(wh, ol, a);
      a = mfma16(wl, oh, a);
    }
  }
  #pragma unroll
  for (int r = 0; r < 16; r++) {
    int row = (r&3) + 8*(r>>2) + 4*hi;
    int c = c0 + wc*32 + row;
    float bv = bo[c];
    size_t o = ((size_t)b*256 + c)*4096 + n0 + wn*64 + lane31;
    Out[o]      = acc0[r] + bv;
    Out[o + 32] = acc1[r] + bv;
  }
}

extern "C" void kernel_launch(void* const* d_in, const int* in_sizes, int n_in,
                              void* d_out, int out_size, void* d_ws, size_t ws_size,
                              hipStream_t stream) {
  const float* x1 = (const float*)d_in[0];
  const float* Wq = (const float*)d_in[1];
  const float* bq = (const float*)d_in[2];
  const float* Wk = (const float*)d_in[3];
  const float* bk = (const float*)d_in[4];
  const float* Wv = (const float*)d_in[5];
  const float* bv = (const float*)d_in[6];
  const float* Wo = (const float*)d_in[7];
  const float* bo = (const float*)d_in[8];

  const size_t NEL = (size_t)2 * 4096 * 256;   // 2M elements per tensor
  u16* Qs = (u16*)d_ws;
  u16* Ks = Qs + NEL;
  u16* Vt = Ks + NEL;
  float* Os = (float*)(Vt + NEL);              // fp32 O, [b][n][256]
  float* out = (float*)d_out;

  qkv_proj_kernel<<<dim3(32, 4, 6), 256, 0, stream>>>(x1, Wq, bq, Wk, bk, Wv, bv, Qs, Ks, Vt);
  attn_kernel<<<dim3(2048), 256, 0, stream>>>(Qs, Ks, Vt, Os);
  oproj_kernel<<<dim3(32, 4, 2), 256, 0, stream>>>(Os, Wo, bo, out);
}

// Round 4
// 159.849 us; speedup vs baseline: 1.5227x; 1.4434x over previous
//
#include <hip/hip_runtime.h>
#include <cmath>

// SelfMutualAttention: b=2, c=256, h=w=64 (n=4096), H=8 heads, d=32.
//  k1 qkv_proj: Q/K -> head-major [b][h][n][32] bf16 (Q pre-scaled by d^-0.5*log2e),
//               V -> tiled [b][h][kvblk][32d][32kv] bf16 (all attn loads dense)
//  k2 attn:     flash, swapped QK^T, unnormalized exp2 accumulation.
//               2 q-tiles (64 rows) per block, split-KV x4 waves, LDS combine.
//  k3 oproj:    O fp32 [b][n][256] -> Wo (hi/lo split both operands) -> fp32 [b][c][n]
//               R2: 64x64 tiles, 512 blocks (was 256 = 1 wave/SIMD).

typedef unsigned int u32;
typedef unsigned short u16;
typedef __attribute__((ext_vector_type(4))) float f32x4;
typedef __attribute__((ext_vector_type(16))) float f32x16;
typedef __attribute__((ext_vector_type(8))) short short8;
typedef __attribute__((ext_vector_type(2))) u32 u32x2;
typedef __attribute__((ext_vector_type(4))) u32 u32x4;

__device__ __forceinline__ u32 cvtpk_bf16(float a, float b) {
  u32 r; asm("v_cvt_pk_bf16_f32 %0, %1, %2" : "=v"(r) : "v"(a), "v"(b)); return r;
}
__device__ __forceinline__ void pl32swap(u32 &a, u32 &b) {
  asm("v_permlane32_swap_b32 %0, %1" : "+v"(a), "+v"(b));
}
__device__ __forceinline__ u16 f2bf(float x) { return (u16)cvtpk_bf16(x, x); }

__device__ __forceinline__ f32x16 mfma16(short8 a, short8 b, f32x16 c) {
  return __builtin_amdgcn_mfma_f32_32x32x16_bf16(a, b, c, 0, 0, 0);
}

// split a float into hi-bf16 (truncated) + lo-bf16 (residual, RNE) pairs packed as words
__device__ __forceinline__ void split2(float a, float b, u32 &hw, u32 &lw) {
  u32 ua = __builtin_bit_cast(u32, a), ub = __builtin_bit_cast(u32, b);
  hw = (ua >> 16) | (ub & 0xffff0000u);
  float ra = a - __builtin_bit_cast(float, ua & 0xffff0000u);
  float rb = b - __builtin_bit_cast(float, ub & 0xffff0000u);
  lw = cvtpk_bf16(ra, rb);
}
__device__ __forceinline__ void split8(f32x4 a, f32x4 b, short8 &hf, short8 &lf) {
  u32 h0,l0,h1,l1,h2,l2,h3,l3;
  split2(a[0],a[1],h0,l0); split2(a[2],a[3],h1,l1);
  split2(b[0],b[1],h2,l2); split2(b[2],b[3],h3,l3);
  u32x4 hv = {h0,h1,h2,h3}, lv = {l0,l1,l2,l3};
  hf = __builtin_bit_cast(short8, hv);
  lf = __builtin_bit_cast(short8, lv);
}

#define LDK 40  // halfword stride of transposed X tile row

// ---------------- k1: fused Q/K/V projection -------------------------------
// grid (32 nblk, 4 cblk, 6 = batch*3+mode), 256 thr
__global__ __launch_bounds__(256) void qkv_proj_kernel(
    const float* __restrict__ X,
    const float* __restrict__ Wq, const float* __restrict__ bq,
    const float* __restrict__ Wk, const float* __restrict__ bk,
    const float* __restrict__ Wv, const float* __restrict__ bv,
    u16* __restrict__ Qh, u16* __restrict__ Kh, u16* __restrict__ V3)
{
  const int mode = blockIdx.z % 3;
  const int b    = blockIdx.z / 3;
  const float* W    = mode==0 ? Wq : (mode==1 ? Wk : Wv);
  const float* bias = mode==0 ? bq : (mode==1 ? bk : bv);
  u16* Out          = mode==0 ? Qh : (mode==1 ? Kh : V3);
  const float qmul  = mode==0 ? (0.17677669529663689f * 1.4426950408889634f) : 1.0f;

  const int c0 = blockIdx.y * 64;
  const int n0 = blockIdx.x * 128;
  const int tid = threadIdx.x;
  const int l = tid & 63, wv = tid >> 6;
  const int lane31 = l & 31, hi = l >> 5;
  const int wc = wv >> 1, wn = wv & 1;
  const int crow = c0 + wc*32 + lane31;
  const int head = blockIdx.y*2 + wc;          // c0+wc*32 >> 5

  __shared__ u16 xt[128 * LDK];

  f32x16 acc0 = {}, acc1 = {};

  for (int kk = 0; kk < 256; kk += 32) {
    __syncthreads();
    #pragma unroll
    for (int t = 0; t < 2; t++) {
      int task = tid + t*256;
      int pair = task >> 5;
      int nc0  = (task & 31) * 4;
      const float* px = X + ((size_t)b*256 + kk + pair*2) * 4096 + n0 + nc0;
      f32x4 xa = *(const f32x4*)px;
      f32x4 xb = *(const f32x4*)(px + 4096);
      #pragma unroll
      for (int i = 0; i < 4; i++) {
        u32 packed = cvtpk_bf16(xa[i], xb[i]);
        *(u32*)(&xt[(nc0+i)*LDK + pair*2]) = packed;
      }
    }
    __syncthreads();
    #pragma unroll
    for (int ks = 0; ks < 2; ks++) {
      const float* pw = W + (size_t)crow*256 + kk + ks*16 + hi*8;
      short8 wh, wl;
      split8(*(const f32x4*)pw, *(const f32x4*)(pw+4), wh, wl);
      short8 bf0 = *(const short8*)(&xt[(wn*64 +      lane31)*LDK + ks*16 + hi*8]);
      short8 bf1 = *(const short8*)(&xt[(wn*64 + 32 + lane31)*LDK + ks*16 + hi*8]);
      acc0 = mfma16(wh, bf0, acc0);
      acc0 = mfma16(wl, bf0, acc0);
      acc1 = mfma16(wh, bf1, acc1);
      acc1 = mfma16(wl, bf1, acc1);
    }
  }

  if (mode == 2) {
    // V3: [b][h][kvblk][dv 32][kv 32] tiles; acc0 -> kvblk, acc1 -> kvblk+1
    const int kvb = (n0 + wn*64) >> 5;
    #pragma unroll
    for (int r = 0; r < 16; r++) {
      int row = (r&3) + 8*(r>>2) + 4*hi;         // dv
      float bv2 = bias[c0 + wc*32 + row];
      size_t o = (((size_t)(b*8 + head)*128 + kvb)*32 + row)*32 + lane31;
      Out[o]        = f2bf(acc0[r] + bv2);
      Out[o + 1024] = f2bf(acc1[r] + bv2);
    }
  } else {
    // Q/K head-major: [b][h][n][32]
    int n = n0 + wn*64 + lane31;
    #pragma unroll
    for (int j = 0; j < 2; j++) {
      const f32x16 &a = j ? acc1 : acc0;
      size_t base = ((size_t)(b*8 + head)*4096 + n + j*32) << 5;
      #pragma unroll
      for (int g = 0; g < 4; g++) {
        int cb = c0 + wc*32 + 8*g + 4*hi;
        int dd = 8*g + 4*hi;
        float v0 = (a[4*g+0] + bias[cb+0]) * qmul;
        float v1 = (a[4*g+1] + bias[cb+1]) * qmul;
        float v2 = (a[4*g+2] + bias[cb+2]) * qmul;
        float v3 = (a[4*g+3] + bias[cb+3]) * qmul;
        u32x2 pk = { cvtpk_bf16(v0, v1), cvtpk_bf16(v2, v3) };
        *(u32x2*)(&Out[base + dd]) = pk;
      }
    }
  }
}

// ---------------- k2: fused flash attention --------------------------------
// grid 1024 blocks x 256 thr. Block = 64 q-rows (2 MFMA tiles) of one (b,h);
// 4 waves each own a 1024-row KV quarter; LDS combine at the end.
__global__ __launch_bounds__(256, 4) void attn_kernel(
    const u16* __restrict__ Qh, const u16* __restrict__ Kh,
    const u16* __restrict__ V3, float* __restrict__ Os)
{
  // XCD swizzle: all q-groups of one (b,h) on one XCD -> KV L2-resident
  const int fid  = blockIdx.x;
  const int xcd  = fid & 7, j = fid >> 3;       // j in [0,128)
  const int bh   = xcd + 8 * (j >> 6);          // 2 bh per XCD
  const int qgrp = j & 63;
  const int b = bh >> 3, h = bh & 7;

  const int tid = threadIdx.x, wv = tid >> 6, l = tid & 63;
  const int lane31 = l & 31, hi = l >> 5;

  const u16* qbase = Qh + (((size_t)bh*4096 + qgrp*64 + lane31) << 5) + hi*8;
  short8 qa0 = *(const short8*)(qbase);          // set A: d 0..15 half
  short8 qa1 = *(const short8*)(qbase + 16);     //        d 16..31
  short8 qb0 = *(const short8*)(qbase + 1024);   // set B (rows +32)
  short8 qb1 = *(const short8*)(qbase + 1040);

  f32x16 accA = {}, accB = {};
  float lsA0 = 0.f, lsA1 = 0.f, lsB0 = 0.f, lsB1 = 0.f;

  const u16* kbase = Kh + (((size_t)bh*4096 + lane31) << 5) + hi*8;
  const u16* vbase = V3 + ((size_t)bh << 17) + lane31*32 + hi*8;

  for (int kvo = 0; kvo < 1024; kvo += 32) {
    const int kv = wv*1024 + kvo;
    const u16* kp = kbase + ((size_t)kv << 5);
    const u16* vp = vbase + ((size_t)(kv >> 5) << 10);
    short8 kc0 = *(const short8*)(kp);           // dense 2KB/wave
    short8 kc1 = *(const short8*)(kp + 16);
    short8 vc0 = *(const short8*)(vp);           // dense 2KB/wave
    short8 vc1 = *(const short8*)(vp + 16);

    // ---- set A ----
    {
      f32x16 s = {};
      s = mfma16(kc0, qa0, s);                   // S^T[kv][q]
      s = mfma16(kc1, qa1, s);
      #pragma unroll
      for (int r = 0; r < 16; r++) s[r] = __builtin_amdgcn_exp2f(s[r]);
      lsA0 += (s[0]+s[1]) + (s[4]+s[5]);
      lsA1 += (s[2]+s[3]) + (s[6]+s[7]);
      lsA0 += (s[8]+s[9]) + (s[12]+s[13]);
      lsA1 += (s[10]+s[11]) + (s[14]+s[15]);
      u32 a0 = cvtpk_bf16(s[0],s[1]),   b0 = cvtpk_bf16(s[4],s[5]);
      u32 c1 = cvtpk_bf16(s[2],s[3]),   d1 = cvtpk_bf16(s[6],s[7]);
      u32 e0 = cvtpk_bf16(s[8],s[9]),   f0 = cvtpk_bf16(s[12],s[13]);
      u32 g1 = cvtpk_bf16(s[10],s[11]), h1 = cvtpk_bf16(s[14],s[15]);
      pl32swap(a0,b0); pl32swap(c1,d1); pl32swap(e0,f0); pl32swap(g1,h1);
      u32x4 u0 = {a0,c1,b0,d1}, u1 = {e0,g1,f0,h1};
      accA = mfma16(__builtin_bit_cast(short8,u0), vc0, accA);
      accA = mfma16(__builtin_bit_cast(short8,u1), vc1, accA);
    }
    // ---- set B ----
    {
      f32x16 s = {};
      s = mfma16(kc0, qb0, s);
      s = mfma16(kc1, qb1, s);
      #pragma unroll
      for (int r = 0; r < 16; r++) s[r] = __builtin_amdgcn_exp2f(s[r]);
      lsB0 += (s[0]+s[1]) + (s[4]+s[5]);
      lsB1 += (s[2]+s[3]) + (s[6]+s[7]);
      lsB0 += (s[8]+s[9]) + (s[12]+s[13]);
      lsB1 += (s[10]+s[11]) + (s[14]+s[15]);
      u32 a0 = cvtpk_bf16(s[0],s[1]),   b0 = cvtpk_bf16(s[4],s[5]);
      u32 c1 = cvtpk_bf16(s[2],s[3]),   d1 = cvtpk_bf16(s[6],s[7]);
      u32 e0 = cvtpk_bf16(s[8],s[9]),   f0 = cvtpk_bf16(s[12],s[13]);
      u32 g1 = cvtpk_bf16(s[10],s[11]), h1 = cvtpk_bf16(s[14],s[15]);
      pl32swap(a0,b0); pl32swap(c1,d1); pl32swap(e0,f0); pl32swap(g1,h1);
      u32x4 u0 = {a0,c1,b0,d1}, u1 = {e0,g1,f0,h1};
      accB = mfma16(__builtin_bit_cast(short8,u0), vc0, accB);
      accB = mfma16(__builtin_bit_cast(short8,u1), vc1, accB);
    }
  }

  // ---- combine the 4 KV-quarter partials via LDS ----
  __shared__ float accbA[4][64][17], accbB[4][64][17];
  __shared__ float lsbA[4][64], lsbB[4][64];

  lsbA[wv][l] = lsA0 + lsA1;
  lsbB[wv][l] = lsB0 + lsB1;
  #pragma unroll
  for (int r = 0; r < 16; r++) { accbA[wv][l][r] = accA[r]; accbB[wv][l][r] = accB[r]; }
  __syncthreads();

  float LtA = (lsbA[0][l]+lsbA[1][l]) + (lsbA[2][l]+lsbA[3][l]);
  float LtB = (lsbB[0][l]+lsbB[1][l]) + (lsbB[2][l]+lsbB[3][l]);
  LtA += __shfl_xor(LtA, 32);
  LtB += __shfl_xor(LtB, 32);
  float LiA = 1.0f / LtA, LiB = 1.0f / LtB;

  #pragma unroll
  for (int i = 0; i < 4; i++) {
    int r = wv*4 + i;
    float oA = (accbA[0][l][r]+accbA[1][l][r]) + (accbA[2][l][r]+accbA[3][l][r]);
    float oB = (accbB[0][l][r]+accbB[1][l][r]) + (accbB[2][l][r]+accbB[3][l][r]);
    int row = (r&3) + 8*(r>>2) + 4*hi;
    float LrA = __shfl(LiA, row);
    float LrB = __shfl(LiB, row);
    int qgA = qgrp*64 + row;
    Os[(((size_t)b*4096 + qgA) << 8) + h*32 + lane31]      = oA * LrA;
    Os[(((size_t)b*4096 + qgA + 32) << 8) + h*32 + lane31] = oB * LrB;
  }
}

// ---------------- k3: output projection ------------------------------------
// grid (64,4,2) = 512 blocks, 64x64 tiles, 1 acc per wave.
__global__ __launch_bounds__(256) void oproj_kernel(
    const float* __restrict__ O, const float* __restrict__ Wo,
    const float* __restrict__ bo, float* __restrict__ Out)
{
  const int b = blockIdx.z, c0 = blockIdx.y*64, n0 = blockIdx.x*64;
  const int tid = threadIdx.x, wv = tid >> 6, l = tid & 63;
  const int lane31 = l & 31, hi = l >> 5;
  const int wc = wv >> 1, wn = wv & 1;
  const int crow = c0 + wc*32 + lane31;
  f32x16 acc = {};

  for (int kk = 0; kk < 256; kk += 16) {
    const float* pw = Wo + (size_t)crow*256 + kk + hi*8;
    short8 wh, wl;
    split8(*(const f32x4*)pw, *(const f32x4*)(pw+4), wh, wl);
    const float* po = O + (((size_t)b*4096 + n0 + wn*32 + lane31) << 8) + kk + hi*8;
    short8 oh, ol;
    split8(*(const f32x4*)po, *(const f32x4*)(po+4), oh, ol);
    acc = mfma16(wh, oh, acc);
    acc = mfma16(wh, ol, acc);
    acc = mfma16(wl, oh, acc);
  }
  #pragma unroll
  for (int r = 0; r < 16; r++) {
    int row = (r&3) + 8*(r>>2) + 4*hi;
    int c = c0 + wc*32 + row;
    float bv = bo[c];
    size_t o = ((size_t)b*256 + c)*4096 + n0 + wn*32 + lane31;
    Out[o] = acc[r] + bv;
  }
}

extern "C" void kernel_launch(void* const* d_in, const int* in_sizes, int n_in,
                              void* d_out, int out_size, void* d_ws, size_t ws_size,
                              hipStream_t stream) {
  const float* x1 = (const float*)d_in[0];
  const float* Wq = (const float*)d_in[1];
  const float* bq = (const float*)d_in[2];
  const float* Wk = (const float*)d_in[3];
  const float* bk = (const float*)d_in[4];
  const float* Wv = (const float*)d_in[5];
  const float* bv = (const float*)d_in[6];
  const float* Wo = (const float*)d_in[7];
  const float* bo = (const float*)d_in[8];

  const size_t NEL = (size_t)2 * 4096 * 256;   // 2M elements per tensor
  u16* Qh = (u16*)d_ws;
  u16* Kh = Qh + NEL;
  u16* V3 = Kh + NEL;
  float* Os = (float*)(V3 + NEL);              // fp32 O, [b][n][256]
  float* out = (float*)d_out;

  qkv_proj_kernel<<<dim3(32, 4, 6), 256, 0, stream>>>(x1, Wq, bq, Wk, bk, Wv, bv, Qh, Kh, V3);
  attn_kernel<<<dim3(1024), 256, 0, stream>>>(Qh, Kh, V3, Os);
  oproj_kernel<<<dim3(64, 4, 2), 256, 0, stream>>>(Os, Wo, bo, out);
}

// Round 5
// 148.087 us; speedup vs baseline: 1.6436x; 1.0794x over previous
//
#include <hip/hip_runtime.h>
#include <cmath>

// SelfMutualAttention: b=2, c=256, n=4096, H=8, d=32.
// R4: fragment-layout pipeline. All GEMM operands pre-packed into MFMA
// fragment tiles so every load is a dense 1KB wave-load (no TA scatter,
// no in-GEMM LDS, no barriers in projections).
//  k0 prep:  X [b][c][n] fp32 -> Xa bf16 A-frag tiles [b][nt][kt][64][8]
//            W* fp32 -> Wpk hi/lo bf16 frag planes [mat][pl][kt][ct][64][8]
//            (Wq pre-scaled by d^-0.5*log2e)
//  k1 qkv:   mfma(W, Xa): regs=c, lanes=n. Q/K stored as frag tiles
//            [bh][nt][kt2][64][8] (slot-permutation consistent Q<->K),
//            V stored [bh][kvt][dv32][kv32]. No LDS, no barriers.
//  k2 attn:  flash, swapped QK^T, unnormalized exp2 accumulation, split-KV x4,
//            depth-1 K/V prefetch; epilogue combines via LDS *transposed* and
//            emits O as hi/lo bf16 fragment planes.
//  k3 oproj: mfma(Wo_frag, Oa_frag) x3 (hi/lo) -> fp32 [b][c][n].

typedef unsigned int u32;
typedef unsigned short u16;
typedef __attribute__((ext_vector_type(4))) float f32x4;
typedef __attribute__((ext_vector_type(16))) float f32x16;
typedef __attribute__((ext_vector_type(8))) short short8;
typedef __attribute__((ext_vector_type(4))) u32 u32x4;

__device__ __forceinline__ u32 cvtpk_bf16(float a, float b) {
  u32 r; asm("v_cvt_pk_bf16_f32 %0, %1, %2" : "=v"(r) : "v"(a), "v"(b)); return r;
}
__device__ __forceinline__ void pl32swap(u32 &a, u32 &b) {
  asm("v_permlane32_swap_b32 %0, %1" : "+v"(a), "+v"(b));
}
__device__ __forceinline__ u16 f2bf(float x) { return (u16)cvtpk_bf16(x, x); }

__device__ __forceinline__ f32x16 mfma16(short8 a, short8 b, f32x16 c) {
  return __builtin_amdgcn_mfma_f32_32x32x16_bf16(a, b, c, 0, 0, 0);
}

// hi = truncated bf16, lo = residual (RNE) -- packed pairs
__device__ __forceinline__ void split2(float a, float b, u32 &hw, u32 &lw) {
  u32 ua = __builtin_bit_cast(u32, a), ub = __builtin_bit_cast(u32, b);
  hw = (ua >> 16) | (ub & 0xffff0000u);
  float ra = a - __builtin_bit_cast(float, ua & 0xffff0000u);
  float rb = b - __builtin_bit_cast(float, ub & 0xffff0000u);
  lw = cvtpk_bf16(ra, rb);
}
__device__ __forceinline__ void split8(f32x4 a, f32x4 b, short8 &hf, short8 &lf) {
  u32 h0,l0,h1,l1,h2,l2,h3,l3;
  split2(a[0],a[1],h0,l0); split2(a[2],a[3],h1,l1);
  split2(b[0],b[1],h2,l2); split2(b[2],b[3],h3,l3);
  u32x4 hv = {h0,h1,h2,h3}, lv = {l0,l1,l2,l3};
  hf = __builtin_bit_cast(short8, hv);
  lf = __builtin_bit_cast(short8, lv);
}

// D row for (reg r, lane-hi): (r&3) + 8*((r>>2)&1) + 4*hi + 16*(r>>3)
__device__ __forceinline__ int rowmap(int r, int hi) {
  return (r & 3) + 8 * ((r >> 2) & 1) + 4 * hi + 16 * (r >> 3);
}

#define QMUL (0.17677669529663689f * 1.4426950408889634f)  // d^-0.5 * log2e
#define WPLANE 65536   // u16 stride between hi/lo planes of one W matrix
#define WMAT  131072   // u16 stride between packed W matrices

// ---------------- k0: prep (X transpose-to-frags + W pack) -----------------
// grid 384 blocks x 256 thr: bx<256 -> X transpose, else W pack.
__global__ __launch_bounds__(256) void prep_kernel(
    const float* __restrict__ X,
    const float* __restrict__ Wq, const float* __restrict__ Wk,
    const float* __restrict__ Wv, const float* __restrict__ Wo,
    u16* __restrict__ Xa, u16* __restrict__ Wpk)
{
  const int bx = blockIdx.x, tid = threadIdx.x;
  if (bx < 256) {
    __shared__ float lt[32 * 257];   // [n 32][c 256+1] -> conflict-free both phases
    const int b = bx >> 7, ntile = bx & 127, n0 = ntile * 32;
    const int nn = tid & 31, cg = tid >> 5;
    #pragma unroll 4
    for (int i = 0; i < 32; i++) {
      int c = i * 8 + cg;
      lt[nn * 257 + c] = X[((size_t)b * 256 + c) * 4096 + n0 + nn];
    }
    __syncthreads();
    const int lane = tid & 63, w = tid >> 6;
    const int l31 = lane & 31, fh = lane >> 5;
    #pragma unroll
    for (int kk = 0; kk < 4; kk++) {
      int kt = w * 4 + kk;
      const float* p = &lt[l31 * 257 + kt * 16 + fh * 8];
      u32x4 pk = { cvtpk_bf16(p[0],p[1]), cvtpk_bf16(p[2],p[3]),
                   cvtpk_bf16(p[4],p[5]), cvtpk_bf16(p[6],p[7]) };
      *(u32x4*)(&Xa[(((size_t)b * 128 + ntile) * 16 + kt) * 512 + lane * 8]) = pk;
    }
  } else {
    // job j: lane 64 | ct 8 | kt 16 | mat 4   (32768 jobs)
    const int j = (bx - 256) * 256 + tid;
    const int lane = j & 63, ct = (j >> 6) & 7, kt = (j >> 9) & 15, mat = j >> 13;
    const float* W = mat == 0 ? Wq : (mat == 1 ? Wk : (mat == 2 ? Wv : Wo));
    const int c = ct * 32 + (lane & 31);
    const int k0 = kt * 16 + (lane >> 5) * 8;
    f32x4 a = *(const f32x4*)(W + (size_t)c * 256 + k0);
    f32x4 b = *(const f32x4*)(W + (size_t)c * 256 + k0 + 4);
    if (mat == 0) {
      #pragma unroll
      for (int i = 0; i < 4; i++) { a[i] *= QMUL; b[i] *= QMUL; }
    }
    short8 wh, wl; split8(a, b, wh, wl);
    size_t base = ((size_t)mat * 2) * WPLANE + ((size_t)kt * 8 + ct) * 512 + lane * 8;
    *(short8*)(&Wpk[base]) = wh;
    *(short8*)(&Wpk[base + WPLANE]) = wl;
  }
}

// ---------------- k1: QKV projection (fragment streaming GEMM) -------------
// grid (64 ngrp, 1, 6 = b*3+mode), 256 thr. Wave: n-tile 32 x c-half 128.
__global__ __launch_bounds__(256) void qkv_kernel(
    const u16* __restrict__ Xa, const u16* __restrict__ Wpk,
    const float* __restrict__ bq, const float* __restrict__ bk,
    const float* __restrict__ bv,
    u16* __restrict__ Qf, u16* __restrict__ Kf, u16* __restrict__ V3)
{
  const int z = blockIdx.z, mode = z % 3, b = z / 3;
  const int tid = threadIdx.x, lane = tid & 63, wv = tid >> 6;
  const int wn = wv & 1, wcH = wv >> 1;
  const int ntile = blockIdx.x * 2 + wn;     // 0..127
  const int l31 = lane & 31, fh = lane >> 5;

  const u16* Amat = Xa + ((size_t)b * 128 + ntile) * 8192;
  const u16* Bmat = Wpk + (size_t)mode * WMAT;

  f32x16 acc[4] = {{}, {}, {}, {}};
  for (int kt = 0; kt < 16; kt++) {
    short8 xa = *(const short8*)(Amat + kt * 512 + lane * 8);
    #pragma unroll
    for (int i = 0; i < 4; i++) {
      int ct = wcH * 4 + i;
      const u16* wp = Bmat + ((size_t)kt * 8 + ct) * 512 + lane * 8;
      short8 wh = *(const short8*)(wp);
      short8 wl = *(const short8*)(wp + WPLANE);
      acc[i] = mfma16(wh, xa, acc[i]);   // A=W (regs=c), B=Xa (lanes=n)
      acc[i] = mfma16(wl, xa, acc[i]);
    }
  }

  const float* bias = mode == 0 ? bq : (mode == 1 ? bk : bv);
  const float bscale = mode == 0 ? QMUL : 1.0f;

  if (mode == 2) {
    // V3 [bh][kvt=ntile][dv 32][kv 32]; regs=dv, lanes=kv -> dense segments
    #pragma unroll
    for (int i = 0; i < 4; i++) {
      int head = wcH * 4 + i;
      size_t tb = (((size_t)(b * 8 + head) * 128 + ntile) * 32) * 32;
      #pragma unroll
      for (int r = 0; r < 16; r++) {
        int dv = rowmap(r, fh);
        V3[tb + (size_t)dv * 32 + l31] = f2bf(acc[i][r] + bias[head * 32 + dv]);
      }
    }
  } else {
    // Q/K fragment tiles [bh][nt][kt2][64][8]; thread holds 16 c-values of
    // its n=l31 column -> pack two short8 (kt2=0/1), slots = natural D order.
    u16* Out = mode == 0 ? Qf : Kf;
    #pragma unroll
    for (int i = 0; i < 4; i++) {
      int head = wcH * 4 + i;
      size_t nb = (((size_t)(b * 8 + head) * 128 + ntile) * 2) * 512;
      #pragma unroll
      for (int kt2 = 0; kt2 < 2; kt2++) {
        float v[8];
        #pragma unroll
        for (int e = 0; e < 8; e++) {
          int c = head * 32 + rowmap(kt2 * 8 + e, fh);
          v[e] = acc[i][kt2 * 8 + e] + bscale * bias[c];
        }
        u32x4 pk = { cvtpk_bf16(v[0],v[1]), cvtpk_bf16(v[2],v[3]),
                     cvtpk_bf16(v[4],v[5]), cvtpk_bf16(v[6],v[7]) };
        *(u32x4*)(&Out[nb + (size_t)kt2 * 512 + lane * 8]) = pk;
      }
    }
  }
}

// ---------------- k2: fused flash attention --------------------------------
// grid 1024 x 256. Block = 64 q-rows of one (b,h); 4 waves split KV x4;
// LDS-transposed combine -> O emitted as hi/lo bf16 fragment planes.
__global__ __launch_bounds__(256, 4) void attn_kernel(
    const u16* __restrict__ Qf, const u16* __restrict__ Kf,
    const u16* __restrict__ V3, u16* __restrict__ OaH, u16* __restrict__ OaL)
{
  const int fid = blockIdx.x;
  const int xcd = fid & 7, j = fid >> 3;
  const int bh = xcd + 8 * (j >> 6);   // XCD swizzle: (b,h) pinned per XCD
  const int qgrp = j & 63;
  const int b = bh >> 3, h = bh & 7;

  const int tid = threadIdx.x, wv = tid >> 6, lane = tid & 63;
  const int l31 = lane & 31, fh = lane >> 5;

  const u16* qfb = Qf + (size_t)bh * 131072 + (size_t)(qgrp * 2) * 1024 + lane * 8;
  short8 qa0 = *(const short8*)(qfb);
  short8 qa1 = *(const short8*)(qfb + 512);
  short8 qb0 = *(const short8*)(qfb + 1024);
  short8 qb1 = *(const short8*)(qfb + 1536);

  const u16* kfb = Kf + (size_t)bh * 131072;
  const u16* vfb = V3 + (size_t)bh * 131072;

  f32x16 accA = {}, accB = {};
  float lsA0 = 0.f, lsA1 = 0.f, lsB0 = 0.f, lsB1 = 0.f;

  int kvt = wv * 32;
  short8 kc0 = *(const short8*)(kfb + (size_t)kvt * 1024 + lane * 8);
  short8 kc1 = *(const short8*)(kfb + (size_t)kvt * 1024 + 512 + lane * 8);
  short8 vc0 = *(const short8*)(vfb + (size_t)kvt * 1024 + l31 * 32 + fh * 8);
  short8 vc1 = *(const short8*)(vfb + (size_t)kvt * 1024 + l31 * 32 + fh * 8 + 16);

  for (int it = 0; it < 32; it++) {
    // depth-1 prefetch (wraps within this wave's KV quarter)
    int nx = wv * 32 + ((it + 1) & 31);
    const u16* kpn = kfb + (size_t)nx * 1024 + lane * 8;
    const u16* vpn = vfb + (size_t)nx * 1024 + l31 * 32 + fh * 8;
    short8 kn0 = *(const short8*)(kpn);
    short8 kn1 = *(const short8*)(kpn + 512);
    short8 vn0 = *(const short8*)(vpn);
    short8 vn1 = *(const short8*)(vpn + 16);

    { // ---- q-set A ----
      f32x16 s = {};
      s = mfma16(kc0, qa0, s);
      s = mfma16(kc1, qa1, s);
      #pragma unroll
      for (int r = 0; r < 16; r++) s[r] = __builtin_amdgcn_exp2f(s[r]);
      lsA0 += (s[0]+s[1]) + (s[4]+s[5]);
      lsA1 += (s[2]+s[3]) + (s[6]+s[7]);
      lsA0 += (s[8]+s[9]) + (s[12]+s[13]);
      lsA1 += (s[10]+s[11]) + (s[14]+s[15]);
      u32 a0 = cvtpk_bf16(s[0],s[1]),   b0 = cvtpk_bf16(s[4],s[5]);
      u32 c1 = cvtpk_bf16(s[2],s[3]),   d1 = cvtpk_bf16(s[6],s[7]);
      u32 e0 = cvtpk_bf16(s[8],s[9]),   f0 = cvtpk_bf16(s[12],s[13]);
      u32 g1 = cvtpk_bf16(s[10],s[11]), h1 = cvtpk_bf16(s[14],s[15]);
      pl32swap(a0,b0); pl32swap(c1,d1); pl32swap(e0,f0); pl32swap(g1,h1);
      u32x4 u0 = {a0,c1,b0,d1}, u1 = {e0,g1,f0,h1};
      accA = mfma16(__builtin_bit_cast(short8,u0), vc0, accA);
      accA = mfma16(__builtin_bit_cast(short8,u1), vc1, accA);
    }
    { // ---- q-set B ----
      f32x16 s = {};
      s = mfma16(kc0, qb0, s);
      s = mfma16(kc1, qb1, s);
      #pragma unroll
      for (int r = 0; r < 16; r++) s[r] = __builtin_amdgcn_exp2f(s[r]);
      lsB0 += (s[0]+s[1]) + (s[4]+s[5]);
      lsB1 += (s[2]+s[3]) + (s[6]+s[7]);
      lsB0 += (s[8]+s[9]) + (s[12]+s[13]);
      lsB1 += (s[10]+s[11]) + (s[14]+s[15]);
      u32 a0 = cvtpk_bf16(s[0],s[1]),   b0 = cvtpk_bf16(s[4],s[5]);
      u32 c1 = cvtpk_bf16(s[2],s[3]),   d1 = cvtpk_bf16(s[6],s[7]);
      u32 e0 = cvtpk_bf16(s[8],s[9]),   f0 = cvtpk_bf16(s[12],s[13]);
      u32 g1 = cvtpk_bf16(s[10],s[11]), h1 = cvtpk_bf16(s[14],s[15]);
      pl32swap(a0,b0); pl32swap(c1,d1); pl32swap(e0,f0); pl32swap(g1,h1);
      u32x4 u0 = {a0,c1,b0,d1}, u1 = {e0,g1,f0,h1};
      accB = mfma16(__builtin_bit_cast(short8,u0), vc0, accB);
      accB = mfma16(__builtin_bit_cast(short8,u1), vc1, accB);
    }
    kc0 = kn0; kc1 = kn1; vc0 = vn0; vc1 = vn1;
  }

  // ---- combine 4 KV-quarter partials; emit O fragment planes ----
  __shared__ float accbA[4][64][17], accbB[4][64][17];
  __shared__ float lsb2[2][4][64];

  lsb2[0][wv][lane] = lsA0 + lsA1;
  lsb2[1][wv][lane] = lsB0 + lsB1;
  #pragma unroll
  for (int r = 0; r < 16; r++) { accbA[wv][lane][r] = accA[r]; accbB[wv][lane][r] = accB[r]; }
  __syncthreads();

  // wave w -> (set = w&1, kt = w>>1). Thread: q' = l31, c-slots by (fh,e).
  const int set = wv & 1, kt = wv >> 1;
  const int qp = l31;
  float Lt = 0.f;
  #pragma unroll
  for (int w2 = 0; w2 < 4; w2++) Lt += lsb2[set][w2][qp] + lsb2[set][w2][qp + 32];
  const float Linv = 1.0f / Lt;

  const int hi_w = (qp >> 2) & 1;
  const int rr = (qp & 3) + ((qp >> 3) << 2);
  float o[8];
  #pragma unroll
  for (int e = 0; e < 8; e++) {
    int idx = (kt * 16 + fh * 8 + e) + 32 * hi_w;   // dv_local + 32*writer_hi
    float v = set ? (accbB[0][idx][rr] + accbB[1][idx][rr] + accbB[2][idx][rr] + accbB[3][idx][rr])
                  : (accbA[0][idx][rr] + accbA[1][idx][rr] + accbA[2][idx][rr] + accbA[3][idx][rr]);
    o[e] = v * Linv;
  }
  f32x4 o0 = {o[0], o[1], o[2], o[3]}, o1 = {o[4], o[5], o[6], o[7]};
  short8 oh, ol; split8(o0, o1, oh, ol);
  const int qt = qgrp * 2 + set, ktg = h * 2 + kt;
  size_t addr = (((size_t)b * 128 + qt) * 16 + ktg) * 512 + lane * 8;
  *(short8*)(&OaH[addr]) = oh;
  *(short8*)(&OaL[addr]) = ol;
}

// ---------------- k3: output projection (fragment GEMM) --------------------
// grid (32 ngrp, 8 ct, 2 b), 256 thr; wave = c-tile 32 x q-tile 32.
__global__ __launch_bounds__(256) void oproj_kernel(
    const u16* __restrict__ OaH, const u16* __restrict__ OaL,
    const u16* __restrict__ Wpk, const float* __restrict__ bo,
    float* __restrict__ Out)
{
  const int b = blockIdx.z, ct = blockIdx.y;
  const int tid = threadIdx.x, lane = tid & 63, wv = tid >> 6;
  const int ntile = blockIdx.x * 4 + wv;     // q-tile 0..127
  const int l31 = lane & 31, fh = lane >> 5;

  const u16* Wo = Wpk + (size_t)3 * WMAT;
  const u16* Ob = OaH + ((size_t)b * 128 + ntile) * 8192;
  const u16* Ol = OaL + ((size_t)b * 128 + ntile) * 8192;

  f32x16 acc = {};
  for (int kt = 0; kt < 16; kt++) {
    const u16* wp = Wo + ((size_t)kt * 8 + ct) * 512 + lane * 8;
    short8 wh = *(const short8*)(wp);
    short8 wl = *(const short8*)(wp + WPLANE);
    short8 oh = *(const short8*)(Ob + kt * 512 + lane * 8);
    short8 ol = *(const short8*)(Ol + kt * 512 + lane * 8);
    acc = mfma16(wh, oh, acc);   // A=Wo (regs=c), B=O (lanes=q)
    acc = mfma16(wh, ol, acc);
    acc = mfma16(wl, oh, acc);
  }
  #pragma unroll
  for (int r = 0; r < 16; r++) {
    int c = ct * 32 + rowmap(r, fh);
    Out[((size_t)b * 256 + c) * 4096 + ntile * 32 + l31] = acc[r] + bo[c];
  }
}

extern "C" void kernel_launch(void* const* d_in, const int* in_sizes, int n_in,
                              void* d_out, int out_size, void* d_ws, size_t ws_size,
                              hipStream_t stream) {
  const float* x1 = (const float*)d_in[0];
  const float* Wq = (const float*)d_in[1];
  const float* bq = (const float*)d_in[2];
  const float* Wk = (const float*)d_in[3];
  const float* bk = (const float*)d_in[4];
  const float* Wv = (const float*)d_in[5];
  const float* bv = (const float*)d_in[6];
  const float* Wo = (const float*)d_in[7];
  const float* bo = (const float*)d_in[8];

  const size_t NEL = (size_t)2 * 4096 * 256;   // 2M elements
  u16* Xa  = (u16*)d_ws;        // reused as OaH after qkv consumes it
  u16* Qf  = Xa + NEL;
  u16* Kf  = Qf + NEL;
  u16* V3  = Kf + NEL;
  u16* OaL = V3 + NEL;
  u16* Wpk = OaL + NEL;         // 524288 u16
  u16* OaH = Xa;
  float* out = (float*)d_out;

  prep_kernel<<<dim3(384), 256, 0, stream>>>(x1, Wq, Wk, Wv, Wo, Xa, Wpk);
  qkv_kernel<<<dim3(64, 1, 6), 256, 0, stream>>>(Xa, Wpk, bq, bk, bv, Qf, Kf, V3);
  attn_kernel<<<dim3(1024), 256, 0, stream>>>(Qf, Kf, V3, OaH, OaL);
  oproj_kernel<<<dim3(32, 8, 2), 256, 0, stream>>>(OaH, OaL, Wpk, bo, out);
}

// Round 6
// 140.829 us; speedup vs baseline: 1.7283x; 1.0515x over previous
//
#include <hip/hip_runtime.h>
#include <cmath>

// SelfMutualAttention: b=2, c=256, n=4096, H=8, d=32.
// R5: attn restructure — kv-permuted V tiles (swap bits 2,3) make the exp2
// output regs a legal PV B-operand (no permlane); PV = mfma(V^T, P) puts
// lanes=q so 1/L is lane-local; lsum via mfma(ones,P) on the MFMA pipe;
// q-sets A/B interleaved for MFMA/VALU overlap. qkv regrid to 768 blocks.

typedef unsigned int u32;
typedef unsigned short u16;
typedef __attribute__((ext_vector_type(4))) float f32x4;
typedef __attribute__((ext_vector_type(16))) float f32x16;
typedef __attribute__((ext_vector_type(8))) short short8;
typedef __attribute__((ext_vector_type(4))) u32 u32x4;

__device__ __forceinline__ u32 cvtpk_bf16(float a, float b) {
  u32 r; asm("v_cvt_pk_bf16_f32 %0, %1, %2" : "=v"(r) : "v"(a), "v"(b)); return r;
}
__device__ __forceinline__ u16 f2bf(float x) { return (u16)cvtpk_bf16(x, x); }

__device__ __forceinline__ f32x16 mfma16(short8 a, short8 b, f32x16 c) {
  return __builtin_amdgcn_mfma_f32_32x32x16_bf16(a, b, c, 0, 0, 0);
}

// hi = truncated bf16, lo = residual (RNE) -- packed pairs
__device__ __forceinline__ void split2(float a, float b, u32 &hw, u32 &lw) {
  u32 ua = __builtin_bit_cast(u32, a), ub = __builtin_bit_cast(u32, b);
  hw = (ua >> 16) | (ub & 0xffff0000u);
  float ra = a - __builtin_bit_cast(float, ua & 0xffff0000u);
  float rb = b - __builtin_bit_cast(float, ub & 0xffff0000u);
  lw = cvtpk_bf16(ra, rb);
}
__device__ __forceinline__ void split8(f32x4 a, f32x4 b, short8 &hf, short8 &lf) {
  u32 h0,l0,h1,l1,h2,l2,h3,l3;
  split2(a[0],a[1],h0,l0); split2(a[2],a[3],h1,l1);
  split2(b[0],b[1],h2,l2); split2(b[2],b[3],h3,l3);
  u32x4 hv = {h0,h1,h2,h3}, lv = {l0,l1,l2,l3};
  hf = __builtin_bit_cast(short8, hv);
  lf = __builtin_bit_cast(short8, lv);
}

// D row for (reg r, lane-hi): (r&3) + 8*((r>>2)&1) + 4*hi + 16*(r>>3)
__device__ __forceinline__ int rowmap(int r, int hi) {
  return (r & 3) + 8 * ((r >> 2) & 1) + 4 * hi + 16 * (r >> 3);
}
// kv -> V-tile storage slot: swap bits 2 and 3
__device__ __forceinline__ int tau(int kv) {
  return (kv & 19) | ((kv & 4) << 1) | ((kv & 8) >> 1);
}

#define QMUL (0.17677669529663689f * 1.4426950408889634f)  // d^-0.5 * log2e
#define WPLANE 65536   // u16 stride between hi/lo planes of one W matrix
#define WMAT  131072   // u16 stride between packed W matrices

// ---------------- k0: prep (X transpose-to-frags + W pack) -----------------
__global__ __launch_bounds__(256) void prep_kernel(
    const float* __restrict__ X,
    const float* __restrict__ Wq, const float* __restrict__ Wk,
    const float* __restrict__ Wv, const float* __restrict__ Wo,
    u16* __restrict__ Xa, u16* __restrict__ Wpk)
{
  const int bx = blockIdx.x, tid = threadIdx.x;
  if (bx < 256) {
    __shared__ float lt[32 * 257];
    const int b = bx >> 7, ntile = bx & 127, n0 = ntile * 32;
    const int nn = tid & 31, cg = tid >> 5;
    #pragma unroll 4
    for (int i = 0; i < 32; i++) {
      int c = i * 8 + cg;
      lt[nn * 257 + c] = X[((size_t)b * 256 + c) * 4096 + n0 + nn];
    }
    __syncthreads();
    const int lane = tid & 63, w = tid >> 6;
    const int l31 = lane & 31, fh = lane >> 5;
    #pragma unroll
    for (int kk = 0; kk < 4; kk++) {
      int kt = w * 4 + kk;
      const float* p = &lt[l31 * 257 + kt * 16 + fh * 8];
      u32x4 pk = { cvtpk_bf16(p[0],p[1]), cvtpk_bf16(p[2],p[3]),
                   cvtpk_bf16(p[4],p[5]), cvtpk_bf16(p[6],p[7]) };
      *(u32x4*)(&Xa[(((size_t)b * 128 + ntile) * 16 + kt) * 512 + lane * 8]) = pk;
    }
  } else {
    const int j = (bx - 256) * 256 + tid;
    const int lane = j & 63, ct = (j >> 6) & 7, kt = (j >> 9) & 15, mat = j >> 13;
    const float* W = mat == 0 ? Wq : (mat == 1 ? Wk : (mat == 2 ? Wv : Wo));
    const int c = ct * 32 + (lane & 31);
    const int k0 = kt * 16 + (lane >> 5) * 8;
    f32x4 a = *(const f32x4*)(W + (size_t)c * 256 + k0);
    f32x4 b = *(const f32x4*)(W + (size_t)c * 256 + k0 + 4);
    if (mat == 0) {
      #pragma unroll
      for (int i = 0; i < 4; i++) { a[i] *= QMUL; b[i] *= QMUL; }
    }
    short8 wh, wl; split8(a, b, wh, wl);
    size_t base = ((size_t)mat * 2) * WPLANE + ((size_t)kt * 8 + ct) * 512 + lane * 8;
    *(short8*)(&Wpk[base]) = wh;
    *(short8*)(&Wpk[base + WPLANE]) = wl;
  }
}

// ---------------- k1: QKV projection (fragment streaming GEMM) -------------
// grid (128 ntile, 1, 6 = b*3+mode), 256 thr. Wave: 1 n-tile x 2 heads.
__global__ __launch_bounds__(256) void qkv_kernel(
    const u16* __restrict__ Xa, const u16* __restrict__ Wpk,
    const float* __restrict__ bq, const float* __restrict__ bk,
    const float* __restrict__ bv,
    u16* __restrict__ Qf, u16* __restrict__ Kf, u16* __restrict__ V3)
{
  const int z = blockIdx.z, mode = z % 3, b = z / 3;
  const int tid = threadIdx.x, lane = tid & 63, wv = tid >> 6;
  const int ntile = blockIdx.x;
  const int l31 = lane & 31, fh = lane >> 5;

  const u16* Amat = Xa + ((size_t)b * 128 + ntile) * 8192;
  const u16* Bmat = Wpk + (size_t)mode * WMAT;

  f32x16 acc[2] = {{}, {}};
  for (int kt = 0; kt < 16; kt++) {
    short8 xa = *(const short8*)(Amat + kt * 512 + lane * 8);
    #pragma unroll
    for (int i = 0; i < 2; i++) {
      int ct = wv * 2 + i;
      const u16* wp = Bmat + ((size_t)kt * 8 + ct) * 512 + lane * 8;
      short8 wh = *(const short8*)(wp);
      short8 wl = *(const short8*)(wp + WPLANE);
      acc[i] = mfma16(wh, xa, acc[i]);   // A=W (regs=c), B=Xa (lanes=n)
      acc[i] = mfma16(wl, xa, acc[i]);
    }
  }

  const float* bias = mode == 0 ? bq : (mode == 1 ? bk : bv);
  const float bscale = mode == 0 ? QMUL : 1.0f;

  if (mode == 2) {
    // V3 [bh][kvt=ntile][dv 32][slot 32], slot = tau(kv): PV A-frag aligned
    const int sl = tau(l31);
    #pragma unroll
    for (int i = 0; i < 2; i++) {
      int head = wv * 2 + i;
      size_t tb = ((size_t)(b * 8 + head) * 128 + ntile) * 1024;
      #pragma unroll
      for (int r = 0; r < 16; r++) {
        int dv = rowmap(r, fh);
        V3[tb + (size_t)dv * 32 + sl] = f2bf(acc[i][r] + bias[head * 32 + dv]);
      }
    }
  } else {
    u16* Out = mode == 0 ? Qf : Kf;
    #pragma unroll
    for (int i = 0; i < 2; i++) {
      int head = wv * 2 + i;
      size_t nb = ((size_t)(b * 8 + head) * 128 + ntile) * 1024;
      #pragma unroll
      for (int kt2 = 0; kt2 < 2; kt2++) {
        float v[8];
        #pragma unroll
        for (int e = 0; e < 8; e++) {
          int c = head * 32 + rowmap(kt2 * 8 + e, fh);
          v[e] = acc[i][kt2 * 8 + e] + bscale * bias[c];
        }
        u32x4 pk = { cvtpk_bf16(v[0],v[1]), cvtpk_bf16(v[2],v[3]),
                     cvtpk_bf16(v[4],v[5]), cvtpk_bf16(v[6],v[7]) };
        *(u32x4*)(&Out[nb + (size_t)kt2 * 512 + lane * 8]) = pk;
      }
    }
  }
}

// ---------------- k2: fused flash attention --------------------------------
// grid 1024 x 256. Block = 64 q-rows of one (b,h); 4 waves split KV x4.
// PV = mfma(V^T_frag, P) -> lanes=q; lsum via mfma(ones, P); no permlane.
__global__ __launch_bounds__(256, 3) void attn_kernel(
    const u16* __restrict__ Qf, const u16* __restrict__ Kf,
    const u16* __restrict__ V3, u16* __restrict__ OaH, u16* __restrict__ OaL)
{
  const int fid = blockIdx.x;
  const int xcd = fid & 7, j = fid >> 3;
  const int bh = xcd + 8 * (j >> 6);   // XCD swizzle: (b,h) pinned per XCD
  const int qgrp = j & 63;
  const int b = bh >> 3, h = bh & 7;

  const int tid = threadIdx.x, wv = tid >> 6, lane = tid & 63;
  const int l31 = lane & 31, fh = lane >> 5;

  const u16* qfb = Qf + (size_t)bh * 131072 + (size_t)(qgrp * 2) * 1024 + lane * 8;
  short8 qa0 = *(const short8*)(qfb);
  short8 qa1 = *(const short8*)(qfb + 512);
  short8 qb0 = *(const short8*)(qfb + 1024);
  short8 qb1 = *(const short8*)(qfb + 1536);

  const u16* kfb = Kf + (size_t)bh * 131072;
  const u16* vfb = V3 + (size_t)bh * 131072;

  const u32x4 onesu = {0x3F803F80u, 0x3F803F80u, 0x3F803F80u, 0x3F803F80u};
  const short8 ones = __builtin_bit_cast(short8, onesu);

  f32x16 accA = {}, accB = {}, sumA = {}, sumB = {};

  for (int it = 0; it < 32; it++) {
    const int kvt = wv * 32 + it;
    const u16* kp = kfb + (size_t)kvt * 1024 + lane * 8;
    const u16* vp = vfb + (size_t)kvt * 1024 + l31 * 32 + fh * 8;
    short8 kc0 = *(const short8*)(kp);
    short8 kc1 = *(const short8*)(kp + 512);
    short8 vc0 = *(const short8*)(vp);
    short8 vc1 = *(const short8*)(vp + 16);

    f32x16 sA = {}, sB = {};
    sA = mfma16(kc0, qa0, sA);   // S^T[kv regs][q lanes]
    sA = mfma16(kc1, qa1, sA);
    sB = mfma16(kc0, qb0, sB);
    sB = mfma16(kc1, qb1, sB);

    #pragma unroll
    for (int r = 0; r < 16; r++) sA[r] = __builtin_amdgcn_exp2f(sA[r]);
    u32x4 uA0 = { cvtpk_bf16(sA[0],sA[1]),  cvtpk_bf16(sA[2],sA[3]),
                  cvtpk_bf16(sA[4],sA[5]),  cvtpk_bf16(sA[6],sA[7]) };
    u32x4 uA1 = { cvtpk_bf16(sA[8],sA[9]),  cvtpk_bf16(sA[10],sA[11]),
                  cvtpk_bf16(sA[12],sA[13]),cvtpk_bf16(sA[14],sA[15]) };
    short8 pA0 = __builtin_bit_cast(short8, uA0);
    short8 pA1 = __builtin_bit_cast(short8, uA1);
    accA = mfma16(vc0, pA0, accA);   // D[dv regs][q lanes]
    accA = mfma16(vc1, pA1, accA);
    sumA = mfma16(ones, pA0, sumA);  // row-sums on the MFMA pipe
    sumA = mfma16(ones, pA1, sumA);

    #pragma unroll
    for (int r = 0; r < 16; r++) sB[r] = __builtin_amdgcn_exp2f(sB[r]);
    u32x4 uB0 = { cvtpk_bf16(sB[0],sB[1]),  cvtpk_bf16(sB[2],sB[3]),
                  cvtpk_bf16(sB[4],sB[5]),  cvtpk_bf16(sB[6],sB[7]) };
    u32x4 uB1 = { cvtpk_bf16(sB[8],sB[9]),  cvtpk_bf16(sB[10],sB[11]),
                  cvtpk_bf16(sB[12],sB[13]),cvtpk_bf16(sB[14],sB[15]) };
    short8 pB0 = __builtin_bit_cast(short8, uB0);
    short8 pB1 = __builtin_bit_cast(short8, uB1);
    accB = mfma16(vc0, pB0, accB);
    accB = mfma16(vc1, pB1, accB);
    sumB = mfma16(ones, pB0, sumB);
    sumB = mfma16(ones, pB1, sumB);
  }

  // ---- combine 4 KV-quarter partials; emit O fragment planes ----
  __shared__ float accb[2][4][64][17];
  __shared__ float lsb[2][4][64];

  #pragma unroll
  for (int r = 0; r < 16; r++) { accb[0][wv][lane][r] = accA[r]; accb[1][wv][lane][r] = accB[r]; }
  lsb[0][wv][lane] = sumA[0];
  lsb[1][wv][lane] = sumB[0];
  __syncthreads();

  const int set = wv & 1, ktl = wv >> 1;
  const float Lt = (lsb[set][0][l31] + lsb[set][1][l31]) +
                   (lsb[set][2][l31] + lsb[set][3][l31]);
  const float Linv = 1.0f / Lt;

  float o[8];
  #pragma unroll
  for (int e = 0; e < 8; e++) {
    int hs = (e >> 2) & 1;
    int r = (e & 3) + 4 * fh + 8 * ktl;
    int li = hs * 32 + l31;
    o[e] = Linv * ((accb[set][0][li][r] + accb[set][1][li][r]) +
                   (accb[set][2][li][r] + accb[set][3][li][r]));
  }
  f32x4 o0 = {o[0], o[1], o[2], o[3]}, o1 = {o[4], o[5], o[6], o[7]};
  short8 oh, ol; split8(o0, o1, oh, ol);
  const int qt = qgrp * 2 + set, ktg = h * 2 + ktl;
  size_t addr = (((size_t)b * 128 + qt) * 16 + ktg) * 512 + lane * 8;
  *(short8*)(&OaH[addr]) = oh;
  *(short8*)(&OaL[addr]) = ol;
}

// ---------------- k3: output projection (fragment GEMM) --------------------
__global__ __launch_bounds__(256) void oproj_kernel(
    const u16* __restrict__ OaH, const u16* __restrict__ OaL,
    const u16* __restrict__ Wpk, const float* __restrict__ bo,
    float* __restrict__ Out)
{
  const int b = blockIdx.z, ct = blockIdx.y;
  const int tid = threadIdx.x, lane = tid & 63, wv = tid >> 6;
  const int ntile = blockIdx.x * 4 + wv;
  const int l31 = lane & 31, fh = lane >> 5;

  const u16* Wo = Wpk + (size_t)3 * WMAT;
  const u16* Ob = OaH + ((size_t)b * 128 + ntile) * 8192;
  const u16* Ol = OaL + ((size_t)b * 128 + ntile) * 8192;

  f32x16 acc = {};
  for (int kt = 0; kt < 16; kt++) {
    const u16* wp = Wo + ((size_t)kt * 8 + ct) * 512 + lane * 8;
    short8 wh = *(const short8*)(wp);
    short8 wl = *(const short8*)(wp + WPLANE);
    short8 oh = *(const short8*)(Ob + kt * 512 + lane * 8);
    short8 ol = *(const short8*)(Ol + kt * 512 + lane * 8);
    acc = mfma16(wh, oh, acc);
    acc = mfma16(wh, ol, acc);
    acc = mfma16(wl, oh, acc);
  }
  #pragma unroll
  for (int r = 0; r < 16; r++) {
    int c = ct * 32 + rowmap(r, fh);
    Out[((size_t)b * 256 + c) * 4096 + ntile * 32 + l31] = acc[r] + bo[c];
  }
}

extern "C" void kernel_launch(void* const* d_in, const int* in_sizes, int n_in,
                              void* d_out, int out_size, void* d_ws, size_t ws_size,
                              hipStream_t stream) {
  const float* x1 = (const float*)d_in[0];
  const float* Wq = (const float*)d_in[1];
  const float* bq = (const float*)d_in[2];
  const float* Wk = (const float*)d_in[3];
  const float* bk = (const float*)d_in[4];
  const float* Wv = (const float*)d_in[5];
  const float* bv = (const float*)d_in[6];
  const float* Wo = (const float*)d_in[7];
  const float* bo = (const float*)d_in[8];

  const size_t NEL = (size_t)2 * 4096 * 256;   // 2M elements
  u16* Xa  = (u16*)d_ws;        // reused as OaH after qkv consumes it
  u16* Qf  = Xa + NEL;
  u16* Kf  = Qf + NEL;
  u16* V3  = Kf + NEL;
  u16* OaL = V3 + NEL;
  u16* Wpk = OaL + NEL;         // 524288 u16
  u16* OaH = Xa;
  float* out = (float*)d_out;

  prep_kernel<<<dim3(384), 256, 0, stream>>>(x1, Wq, Wk, Wv, Wo, Xa, Wpk);
  qkv_kernel<<<dim3(128, 1, 6), 256, 0, stream>>>(Xa, Wpk, bq, bk, bv, Qf, Kf, V3);
  attn_kernel<<<dim3(1024), 256, 0, stream>>>(Qf, Kf, V3, OaH, OaL);
  oproj_kernel<<<dim3(32, 8, 2), 256, 0, stream>>>(OaH, OaL, Wpk, bo, out);
}